// Round 2
// baseline (2364.581 us; speedup 1.0000x reference)
//
#include <hip/hip_runtime.h>

#define NN 20000
#define EE 320000
#define KK 2000
#define SCALE 0.08838834764831845f
#define NT_N 313   // ceil(NN/64)
#define NT_K 32    // ceil(KK/64)

typedef const float* cfp;

static __device__ __forceinline__ float4 ld4(const float* p){ return *reinterpret_cast<const float4*>(p); }
static __device__ __forceinline__ float2 ld2(const float* p){ return *reinterpret_cast<const float2*>(p); }
static __device__ __forceinline__ void st4(float* p, float4 v){ *reinterpret_cast<float4*>(p) = v; }

// ---------------- CSR build ----------------
__global__ __launch_bounds__(256) void k_count(const int* dst, int* deg){
    int i = blockIdx.x*256 + threadIdx.x;
    if (i < EE) atomicAdd(&deg[dst[i]], 1);
}

__global__ __launch_bounds__(256) void k_dinv(const int* deg, float* dinv){
    int n = blockIdx.x*256 + threadIdx.x;
    if (n < NN) dinv[n] = rsqrtf((float)deg[n] + 1.0f);
}

__global__ __launch_bounds__(1024) void k_scan(const int* cnt, int* rows){
    __shared__ int part[1024];
    int t = threadIdx.x;
    int base = t*20;
    int s = 0;
    for (int i = 0; i < 20; ++i){ int idx = base+i; if (idx < NN) s += cnt[idx]; }
    part[t] = s; __syncthreads();
    for (int off = 1; off < 1024; off <<= 1){
        int v = (t >= off) ? part[t-off] : 0;
        __syncthreads();
        part[t] += v;
        __syncthreads();
    }
    int run = part[t] - s;   // exclusive
    for (int i = 0; i < 20; ++i){
        int idx = base+i;
        if (idx < NN){ rows[idx] = run; run += cnt[idx]; }
    }
    if (t == 0) rows[NN] = EE;
}

__global__ __launch_bounds__(256) void k_fill(const int* src, const int* dst, const int* rows,
                                              int* cursor, int* col){
    int i = blockIdx.x*256 + threadIdx.x;
    if (i < EE){
        int d = dst[i];
        int pos = rows[d] + atomicAdd(&cursor[d], 1);
        col[pos] = src[i];
    }
}

// ---------------- GEMM  C[M x 128] = A[M x 128] @ W[128 x 128]  + epilogue ----------------
__global__ __launch_bounds__(512) void gemm128(const float* __restrict__ A, const float* __restrict__ Wm,
                                               float* __restrict__ C, int M,
                                               const float* srow, const float* bias,
                                               const float* resid, int relu){
    __shared__ __align__(16) float Ws[128*132];
    __shared__ float As[64*129];
    int tid = threadIdx.x;
    int r0 = blockIdx.x*64;
    for (int i = tid; i < 128*32; i += 512){
        int r = i >> 5, c4 = (i & 31) * 4;
        float4 v = ld4(Wm + r*128 + c4);
        st4(&Ws[r*132 + c4], v);
    }
    for (int i = tid; i < 64*32; i += 512){
        int r = i >> 5, c4 = (i & 31) * 4;
        float4 v = (r0 + r < M) ? ld4(A + (r0+r)*128 + c4) : make_float4(0,0,0,0);
        As[r*129 + c4+0] = v.x; As[r*129 + c4+1] = v.y;
        As[r*129 + c4+2] = v.z; As[r*129 + c4+3] = v.w;
    }
    __syncthreads();
    int a = tid >> 5;   // 0..15 -> rows 4a..4a+3
    int b = tid & 31;   // 0..31 -> cols 4b..4b+3
    float acc[4][4] = {};
    #pragma unroll 4
    for (int d = 0; d < 128; ++d){
        float4 w = ld4(&Ws[d*132 + 4*b]);
        float wv[4] = {w.x, w.y, w.z, w.w};
        float av[4];
        #pragma unroll
        for (int i = 0; i < 4; ++i) av[i] = As[(4*a+i)*129 + d];
        #pragma unroll
        for (int i = 0; i < 4; ++i)
            #pragma unroll
            for (int j = 0; j < 4; ++j)
                acc[i][j] += av[i]*wv[j];
    }
    int cc = 4*b;
    #pragma unroll
    for (int i = 0; i < 4; ++i){
        int r = r0 + 4*a + i;
        if (r < M){
            float v[4];
            #pragma unroll
            for (int j = 0; j < 4; ++j) v[j] = acc[i][j];
            if (bias){
                #pragma unroll
                for (int j = 0; j < 4; ++j) v[j] += bias[cc+j];
            }
            if (relu){
                #pragma unroll
                for (int j = 0; j < 4; ++j) v[j] = fmaxf(v[j], 0.f);
            }
            if (resid){
                float4 rv = ld4(resid + r*128 + cc);
                v[0]+=rv.x; v[1]+=rv.y; v[2]+=rv.z; v[3]+=rv.w;
            }
            if (srow){
                float sc = srow[r];
                #pragma unroll
                for (int j = 0; j < 4; ++j) v[j] *= sc;
            }
            st4(C + r*128 + cc, make_float4(v[0],v[1],v[2],v[3]));
        }
    }
}

// ---------------- GCN aggregation: out[n] = relu?( dinv[n]*(hp[n] + sum_{in} hp[src]) + b ) ----------------
__global__ __launch_bounds__(256) void gcn_agg(const float* __restrict__ hp, const float* __restrict__ dinv,
                                               const int* __restrict__ rows, const int* __restrict__ col,
                                               const float* __restrict__ bias, float* __restrict__ out, int relu){
    int wid = (int)((blockIdx.x*256 + threadIdx.x) >> 6);
    int lane = threadIdx.x & 63;
    if (wid >= NN) return;
    int f = lane*2;
    float2 acc = ld2(hp + wid*128 + f);
    int s = rows[wid], e = rows[wid+1];
    for (int j = s; j < e; ++j){
        int c = col[j];
        float2 v = ld2(hp + c*128 + f);
        acc.x += v.x; acc.y += v.y;
    }
    float dn = dinv[wid];
    float ox = acc.x*dn + bias[f];
    float oy = acc.y*dn + bias[f+1];
    if (relu){ ox = fmaxf(ox, 0.f); oy = fmaxf(oy, 0.f); }
    *reinterpret_cast<float2*>(out + wid*128 + f) = make_float2(ox, oy);
}

// ---------------- transpose: in [M x 128] -> out [128 x M] ----------------
__global__ __launch_bounds__(256) void transpose128(const float* __restrict__ in, float* __restrict__ out, int M){
    __shared__ float t[64][65];
    int r0 = blockIdx.x*64, c0 = blockIdx.y*64;
    int tid = threadIdx.x;
    for (int i = tid; i < 64*16; i += 256){
        int r = i >> 4, c4 = (i & 15) * 4;
        float4 v = (r0 + r < M) ? ld4(in + (r0+r)*128 + c0 + c4) : make_float4(0,0,0,0);
        t[r][c4+0]=v.x; t[r][c4+1]=v.y; t[r][c4+2]=v.z; t[r][c4+3]=v.w;
    }
    __syncthreads();
    for (int i = tid; i < 64*16; i += 256){
        int c = i >> 4, r4 = (i & 15) * 4;
        if (r0 + r4 < M){
            float4 v = make_float4(t[r4+0][c], t[r4+1][c], t[r4+2][c], t[r4+3][c]);
            st4(out + (size_t)(c0+c)*M + r0 + r4, v);
        }
    }
}

// ---------------- pass1: per-node softmax stats over seed dim ----------------
__global__ __launch_bounds__(256) void attn_pass1(const float* __restrict__ Qt, const float* __restrict__ Kt,
                                                  float* __restrict__ mo, float* __restrict__ zo){
    __shared__ __align__(16) float Kts[128*68];
    __shared__ __align__(16) float Qts[128*68];
    __shared__ float red[16*64];
    __shared__ float tmaxs[64];
    int tid = threadIdx.x;
    int n0 = blockIdx.x*64;
    for (int i = tid; i < 128*16; i += 256){
        int d = i >> 4, c4 = (i & 15) * 4;
        float4 v = (n0 + c4 < NN) ? ld4(Kt + (size_t)d*NN + n0 + c4) : make_float4(0,0,0,0);
        st4(&Kts[d*68 + c4], v);
    }
    int a = tid >> 4;   // 0..15 -> k 4a..
    int b = tid & 15;   // 0..15 -> n 4b..
    float m_r = -1e30f, z_r = 0.f;
    for (int kt = 0; kt < NT_K; ++kt){
        int k0 = kt*64;
        __syncthreads();
        for (int i = tid; i < 128*16; i += 256){
            int d = i >> 4, c4 = (i & 15) * 4;
            float4 v = (k0 + c4 < KK) ? ld4(Qt + (size_t)d*KK + k0 + c4) : make_float4(0,0,0,0);
            st4(&Qts[d*68 + c4], v);
        }
        __syncthreads();
        float sacc[4][4] = {};
        #pragma unroll 4
        for (int d = 0; d < 128; ++d){
            float4 q = ld4(&Qts[d*68 + 4*a]);
            float4 kv = ld4(&Kts[d*68 + 4*b]);
            float qv[4] = {q.x,q.y,q.z,q.w};
            float kk[4] = {kv.x,kv.y,kv.z,kv.w};
            #pragma unroll
            for (int i = 0; i < 4; ++i)
                #pragma unroll
                for (int j = 0; j < 4; ++j)
                    sacc[i][j] += qv[i]*kk[j];
        }
        float lmax[4] = {-1e30f,-1e30f,-1e30f,-1e30f};
        #pragma unroll
        for (int i = 0; i < 4; ++i){
            bool vK = (k0 + 4*a + i) < KK;
            #pragma unroll
            for (int j = 0; j < 4; ++j){
                float s = sacc[i][j]*SCALE;
                sacc[i][j] = s;
                if (vK) lmax[j] = fmaxf(lmax[j], s);
            }
        }
        #pragma unroll
        for (int j = 0; j < 4; ++j) red[a*64 + 4*b + j] = lmax[j];
        __syncthreads();
        if (tid < 64){
            float tm = red[tid];
            for (int u = 1; u < 16; ++u) tm = fmaxf(tm, red[u*64 + tid]);
            tmaxs[tid] = tm;
        }
        __syncthreads();
        float lsum[4] = {0,0,0,0};
        #pragma unroll
        for (int i = 0; i < 4; ++i){
            bool vK = (k0 + 4*a + i) < KK;
            if (vK){
                #pragma unroll
                for (int j = 0; j < 4; ++j)
                    lsum[j] += __expf(sacc[i][j] - tmaxs[4*b + j]);
            }
        }
        #pragma unroll
        for (int j = 0; j < 4; ++j) red[a*64 + 4*b + j] = lsum[j];
        __syncthreads();
        if (tid < 64){
            float ts = 0.f;
            for (int u = 0; u < 16; ++u) ts += red[u*64 + tid];
            float tmv = tmaxs[tid];
            if (tmv > m_r){ z_r = z_r*__expf(m_r - tmv) + ts; m_r = tmv; }
            else { z_r += ts*__expf(tmv - m_r); }
        }
    }
    if (tid < 64 && n0 + tid < NN){
        mo[n0 + tid] = m_r;
        zo[n0 + tid] = 1.f / z_r;
    }
}

// ---------------- pass2: attn[k,d] += sum_n exp(s-m[n])*zinv[n]*V[n,d] ----------------
__global__ __launch_bounds__(256) void attn_pass2(const float* __restrict__ Qt, const float* __restrict__ Kt,
                                                  const float* __restrict__ V, const float* __restrict__ m,
                                                  const float* __restrict__ zinv, float* __restrict__ attn){
    __shared__ __align__(16) float Qts[128*68];
    __shared__ __align__(16) float Kts[128*68];
    __shared__ __align__(16) float Vs[64*128];
    __shared__ __align__(16) float Pt[64*68];
    __shared__ float ms[64], zs[64];
    int tid = threadIdx.x;
    int k0 = blockIdx.x*64;
    for (int i = tid; i < 128*16; i += 256){
        int d = i >> 4, c4 = (i & 15) * 4;
        float4 v = (k0 + c4 < KK) ? ld4(Qt + (size_t)d*KK + k0 + c4) : make_float4(0,0,0,0);
        st4(&Qts[d*68 + c4], v);
    }
    int a = tid >> 4;   // k / output-k role
    int b = tid & 15;   // n / output-d role
    float acc[4][8] = {};
    for (int nt = blockIdx.y; nt < NT_N; nt += 16){
        int n0 = nt*64;
        __syncthreads();
        for (int i = tid; i < 128*16; i += 256){
            int d = i >> 4, c4 = (i & 15) * 4;
            float4 v = (n0 + c4 < NN) ? ld4(Kt + (size_t)d*NN + n0 + c4) : make_float4(0,0,0,0);
            st4(&Kts[d*68 + c4], v);
        }
        for (int i = tid; i < 64*32; i += 256){
            int r = i >> 5, c4 = (i & 31) * 4;
            float4 v = (n0 + r < NN) ? ld4(V + (n0+r)*128 + c4) : make_float4(0,0,0,0);
            st4(&Vs[r*128 + c4], v);
        }
        if (tid < 64){
            int nn = n0 + tid;
            ms[tid] = (nn < NN) ? m[nn] : 0.f;
            zs[tid] = (nn < NN) ? zinv[nn] : 0.f;
        }
        __syncthreads();
        float sacc[4][4] = {};
        #pragma unroll 4
        for (int d = 0; d < 128; ++d){
            float4 q = ld4(&Qts[d*68 + 4*a]);
            float4 kv = ld4(&Kts[d*68 + 4*b]);
            float qv[4] = {q.x,q.y,q.z,q.w};
            float kk[4] = {kv.x,kv.y,kv.z,kv.w};
            #pragma unroll
            for (int i = 0; i < 4; ++i)
                #pragma unroll
                for (int j = 0; j < 4; ++j)
                    sacc[i][j] += qv[i]*kk[j];
        }
        #pragma unroll
        for (int j = 0; j < 4; ++j){
            float mm = ms[4*b + j], zz = zs[4*b + j];
            float p[4];
            #pragma unroll
            for (int i = 0; i < 4; ++i)
                p[i] = __expf(sacc[i][j]*SCALE - mm) * zz;
            st4(&Pt[(4*b + j)*68 + 4*a], make_float4(p[0],p[1],p[2],p[3]));
        }
        __syncthreads();
        #pragma unroll 2
        for (int nn = 0; nn < 64; ++nn){
            float4 p = ld4(&Pt[nn*68 + 4*a]);
            float4 v0 = ld4(&Vs[nn*128 + 8*b]);
            float4 v1 = ld4(&Vs[nn*128 + 8*b + 4]);
            float pr[4] = {p.x,p.y,p.z,p.w};
            float vv[8] = {v0.x,v0.y,v0.z,v0.w,v1.x,v1.y,v1.z,v1.w};
            #pragma unroll
            for (int i = 0; i < 4; ++i)
                #pragma unroll
                for (int j = 0; j < 8; ++j)
                    acc[i][j] += pr[i]*vv[j];
        }
        __syncthreads();
    }
    #pragma unroll
    for (int i = 0; i < 4; ++i){
        int kg = k0 + 4*a + i;
        if (kg < KK){
            #pragma unroll
            for (int j = 0; j < 8; ++j)
                atomicAdd(&attn[kg*128 + 8*b + j], acc[i][j]);
        }
    }
}

// ---------------- pass3: xout[n,d] = sum_k exp(s-m[n])*zinv[n]*xl[k,d] ----------------
__global__ __launch_bounds__(256) void attn_pass3(const float* __restrict__ Qt, const float* __restrict__ Kt,
                                                  const float* __restrict__ xl, const float* __restrict__ m,
                                                  const float* __restrict__ zinv, float* __restrict__ xout){
    __shared__ __align__(16) float Kts[128*68];
    __shared__ __align__(16) float Qts[128*68];
    __shared__ __align__(16) float Xs[64*128];
    __shared__ __align__(16) float P[64*68];
    __shared__ float ms[64], zs[64];
    int tid = threadIdx.x;
    int n0 = blockIdx.x*64;
    for (int i = tid; i < 128*16; i += 256){
        int d = i >> 4, c4 = (i & 15) * 4;
        float4 v = (n0 + c4 < NN) ? ld4(Kt + (size_t)d*NN + n0 + c4) : make_float4(0,0,0,0);
        st4(&Kts[d*68 + c4], v);
    }
    if (tid < 64){
        int nn = n0 + tid;
        ms[tid] = (nn < NN) ? m[nn] : 0.f;
        zs[tid] = (nn < NN) ? zinv[nn] : 0.f;
    }
    int a = tid >> 4;   // s: k rows 4a..   stage2: n rows 4a..
    int b = tid & 15;   // s: n cols 4b..   stage2: d cols 8b..
    float acc[4][8] = {};
    for (int kt = 0; kt < NT_K; ++kt){
        int k0 = kt*64;
        __syncthreads();
        for (int i = tid; i < 128*16; i += 256){
            int d = i >> 4, c4 = (i & 15) * 4;
            float4 v = (k0 + c4 < KK) ? ld4(Qt + (size_t)d*KK + k0 + c4) : make_float4(0,0,0,0);
            st4(&Qts[d*68 + c4], v);
        }
        for (int i = tid; i < 64*32; i += 256){
            int r = i >> 5, c4 = (i & 31) * 4;
            float4 v = (k0 + r < KK) ? ld4(xl + (k0+r)*128 + c4) : make_float4(0,0,0,0);
            st4(&Xs[r*128 + c4], v);
        }
        __syncthreads();
        float sacc[4][4] = {};
        #pragma unroll 4
        for (int d = 0; d < 128; ++d){
            float4 q = ld4(&Qts[d*68 + 4*a]);
            float4 kv = ld4(&Kts[d*68 + 4*b]);
            float qv[4] = {q.x,q.y,q.z,q.w};
            float kk[4] = {kv.x,kv.y,kv.z,kv.w};
            #pragma unroll
            for (int i = 0; i < 4; ++i)
                #pragma unroll
                for (int j = 0; j < 4; ++j)
                    sacc[i][j] += qv[i]*kk[j];
        }
        #pragma unroll
        for (int i = 0; i < 4; ++i){
            bool vK = (k0 + 4*a + i) < KK;
            float p[4];
            #pragma unroll
            for (int j = 0; j < 4; ++j){
                float mm = ms[4*b + j], zz = zs[4*b + j];
                p[j] = vK ? (__expf(sacc[i][j]*SCALE - mm) * zz) : 0.f;
            }
            st4(&P[(4*a + i)*68 + 4*b], make_float4(p[0],p[1],p[2],p[3]));
        }
        __syncthreads();
        #pragma unroll 2
        for (int kk2 = 0; kk2 < 64; ++kk2){
            float4 p = ld4(&P[kk2*68 + 4*a]);
            float4 x0 = ld4(&Xs[kk2*128 + 8*b]);
            float4 x1 = ld4(&Xs[kk2*128 + 8*b + 4]);
            float pr[4] = {p.x,p.y,p.z,p.w};
            float xv[8] = {x0.x,x0.y,x0.z,x0.w,x1.x,x1.y,x1.z,x1.w};
            #pragma unroll
            for (int i = 0; i < 4; ++i)
                #pragma unroll
                for (int j = 0; j < 8; ++j)
                    acc[i][j] += pr[i]*xv[j];
        }
        __syncthreads();
    }
    #pragma unroll
    for (int i = 0; i < 4; ++i){
        int nr = n0 + 4*a + i;
        if (nr < NN){
            st4(xout + nr*128 + 8*b,     make_float4(acc[i][0],acc[i][1],acc[i][2],acc[i][3]));
            st4(xout + nr*128 + 8*b + 4, make_float4(acc[i][4],acc[i][5],acc[i][6],acc[i][7]));
        }
    }
}

// ---------------- LayerNorm over D=128 ----------------
__global__ __launch_bounds__(128) void ln_ker(const float* __restrict__ in, const float* __restrict__ resid,
                                              const float* __restrict__ g, const float* __restrict__ be,
                                              float* __restrict__ out){
    __shared__ float rs[128], rq[128];
    int r = blockIdx.x, t = threadIdx.x;
    float v = in[r*128 + t];
    if (resid) v += resid[r*128 + t];
    rs[t] = v; rq[t] = v*v;
    __syncthreads();
    for (int off = 64; off > 0; off >>= 1){
        if (t < off){ rs[t] += rs[t+off]; rq[t] += rq[t+off]; }
        __syncthreads();
    }
    float mean = rs[0]*(1.f/128.f);
    float var = rq[0]*(1.f/128.f) - mean*mean;
    out[r*128 + t] = (v - mean)*rsqrtf(var + 1e-5f)*g[t] + be[t];
}

// ---------------- launcher ----------------
extern "C" void kernel_launch(void* const* d_in, const int* in_sizes, int n_in,
                              void* d_out, int out_size, void* d_ws, size_t ws_size,
                              hipStream_t stream){
    cfp x  = (cfp)d_in[0];
    const int* ei = (const int*)d_in[1];
    const int* esrc = ei;
    const int* edst = ei + EE;
    cfp W1=(cfp)d_in[3], b1=(cfp)d_in[4], W2=(cfp)d_in[5], b2=(cfp)d_in[6];
    cfp S =(cfp)d_in[7];
    cfp Wq=(cfp)d_in[8],  bq=(cfp)d_in[9],  Wk=(cfp)d_in[10], bk=(cfp)d_in[11];
    cfp Wv=(cfp)d_in[12], bv=(cfp)d_in[13], Wo=(cfp)d_in[14], bo=(cfp)d_in[15];
    cfp g0=(cfp)d_in[16], be0=(cfp)d_in[17], g1=(cfp)d_in[18], be1=(cfp)d_in[19];
    cfp Wl=(cfp)d_in[20], bl=(cfp)d_in[21], W3=(cfp)d_in[22], b3=(cfp)d_in[23];
    cfp W4=(cfp)d_in[24], b4=(cfp)d_in[25], W5=(cfp)d_in[26], b5=(cfp)d_in[27];

    char* wsb = (char*)d_ws;
    int*   deg    = (int*)  (wsb + 0);
    float* dinv   = (float*)(wsb + 81920);
    int*   rows   = (int*)  (wsb + 163840);
    int*   cursor = (int*)  (wsb + 245760);
    int*   col    = (int*)  (wsb + 327680);
    float* mbuf   = (float*)(wsb + 1638400);
    float* zinv   = (float*)(wsb + 1720320);
    float* Qb     = (float*)(wsb + 2097152);
    float* attn   = (float*)(wsb + 3145728);
    float* o1     = (float*)(wsb + 4194304);
    float* o2     = (float*)(wsb + 5242880);
    float* o3     = (float*)(wsb + 6291456);
    float* xlb    = (float*)(wsb + 7340032);
    float* Qt     = (float*)(wsb + 8388608);
    float* NB0    = (float*)(wsb + 10485760);
    float* NB1    = (float*)(wsb + 20971520);
    float* NB2    = (float*)(wsb + 31457280);
    float* NB3    = (float*)(wsb + 41943040);
    float* Kt     = (float*)(wsb + 52428800);
    float* outp   = (float*)d_out;

    (void)hipMemsetAsync(deg, 0, NN*sizeof(int), stream);
    (void)hipMemsetAsync(cursor, 0, NN*sizeof(int), stream);
    (void)hipMemsetAsync(attn, 0, KK*128*sizeof(float), stream);

    // CSR build
    k_count<<<1250, 256, 0, stream>>>(edst, deg);
    k_dinv<<<79, 256, 0, stream>>>(deg, dinv);
    k_scan<<<1, 1024, 0, stream>>>(deg, rows);
    k_fill<<<1250, 256, 0, stream>>>(esrc, edst, rows, cursor, col);

    const int GN = NT_N;   // ceil(NN/64)
    const int GK = NT_K;   // ceil(KK/64)

    // GCN1: h1 = relu(agg(x@W1 * dinv) * dinv + b1)
    gemm128<<<GN, 512, 0, stream>>>(x, W1, NB0, NN, dinv, nullptr, nullptr, 0);
    gcn_agg<<<5000, 256, 0, stream>>>(NB0, dinv, rows, col, b1, NB1, 1);
    // GCN2
    gemm128<<<GN, 512, 0, stream>>>(NB1, W2, NB0, NN, dinv, nullptr, nullptr, 0);
    gcn_agg<<<5000, 256, 0, stream>>>(NB0, dinv, rows, col, b2, NB2, 1);   // h2
    // Kd = gcn(h2, Wk, bk)
    gemm128<<<GN, 512, 0, stream>>>(NB2, Wk, NB0, NN, dinv, nullptr, nullptr, 0);
    gcn_agg<<<5000, 256, 0, stream>>>(NB0, dinv, rows, col, bk, NB1, 0);   // Kd
    // Vd = gcn(h2, Wv, bv)
    gemm128<<<GN, 512, 0, stream>>>(NB2, Wv, NB0, NN, dinv, nullptr, nullptr, 0);
    gcn_agg<<<5000, 256, 0, stream>>>(NB0, dinv, rows, col, bv, NB3, 0);   // Vd
    // Q = S@Wq + bq
    gemm128<<<GK, 512, 0, stream>>>(S, Wq, Qb, KK, nullptr, bq, nullptr, 0);
    // transposes
    transpose128<<<dim3(GK, 2), 256, 0, stream>>>(Qb, Qt, KK);
    transpose128<<<dim3(GN, 2), 256, 0, stream>>>(NB1, Kt, NN);
    // attention
    attn_pass1<<<GN, 256, 0, stream>>>(Qt, Kt, mbuf, zinv);
    attn_pass2<<<dim3(GK, 16), 256, 0, stream>>>(Qt, Kt, NB3, mbuf, zinv, attn);
    // out = LN(Q + attn)
    ln_ker<<<KK, 128, 0, stream>>>(attn, Qb, g0, be0, o1);
    // o2 = o1 + relu(o1@Wo + bo)
    gemm128<<<GK, 512, 0, stream>>>(o1, Wo, o2, KK, nullptr, bo, o1, 1);
    ln_ker<<<KK, 128, 0, stream>>>(o2, nullptr, g1, be1, o3);
    // xl = o3@Wl + bl
    gemm128<<<GK, 512, 0, stream>>>(o3, Wl, xlb, KK, nullptr, bl, nullptr, 0);
    // x_out = A^T @ xl
    attn_pass3<<<GN, 256, 0, stream>>>(Qt, Kt, xlb, mbuf, zinv, NB0);
    // GCN3
    gemm128<<<GN, 512, 0, stream>>>(NB0, W3, NB1, NN, dinv, nullptr, nullptr, 0);
    gcn_agg<<<5000, 256, 0, stream>>>(NB1, dinv, rows, col, b3, NB2, 1);
    // GCN4
    gemm128<<<GN, 512, 0, stream>>>(NB2, W4, NB0, NN, dinv, nullptr, nullptr, 0);
    gcn_agg<<<5000, 256, 0, stream>>>(NB0, dinv, rows, col, b4, NB1, 1);
    // GCN5 -> d_out
    gemm128<<<GN, 512, 0, stream>>>(NB1, W5, NB0, NN, dinv, nullptr, nullptr, 0);
    gcn_agg<<<5000, 256, 0, stream>>>(NB0, dinv, rows, col, b5, outp, 0);
}

// Round 3
// 930.894 us; speedup vs baseline: 2.5401x; 2.5401x over previous
//
#include <hip/hip_runtime.h>

#define NN 20000
#define EE 320000
#define KK 2000
#define SCALE 0.08838834764831845f

typedef const float* cfp;
typedef __attribute__((ext_vector_type(8))) short sh8;
typedef __attribute__((ext_vector_type(4))) float f32x4;

static __device__ __forceinline__ float4 ld4(const float* p){ return *reinterpret_cast<const float4*>(p); }
static __device__ __forceinline__ float2 ld2(const float* p){ return *reinterpret_cast<const float2*>(p); }
static __device__ __forceinline__ void st4(float* p, float4 v){ *reinterpret_cast<float4*>(p) = v; }

static __device__ __forceinline__ unsigned short f2bf(float f){
    unsigned int u = __float_as_uint(f);
    u = (u + 0x7FFFu + ((u >> 16) & 1u)) >> 16;
    return (unsigned short)u;
}
static __device__ __forceinline__ float bf2f(unsigned short h){
    return __uint_as_float(((unsigned int)h) << 16);
}

// ---------------- CSR build ----------------
__global__ __launch_bounds__(256) void k_count(const int* dst, int* deg){
    int i = blockIdx.x*256 + threadIdx.x;
    if (i < EE) atomicAdd(&deg[dst[i]], 1);
}

__global__ __launch_bounds__(256) void k_dinv(const int* deg, float* dinv){
    int n = blockIdx.x*256 + threadIdx.x;
    if (n < NN) dinv[n] = rsqrtf((float)deg[n] + 1.0f);
}

__global__ __launch_bounds__(1024) void k_scan(const int* cnt, int* rows){
    __shared__ int part[1024];
    int t = threadIdx.x;
    int base = t*20;
    int s = 0;
    for (int i = 0; i < 20; ++i){ int idx = base+i; if (idx < NN) s += cnt[idx]; }
    part[t] = s; __syncthreads();
    for (int off = 1; off < 1024; off <<= 1){
        int v = (t >= off) ? part[t-off] : 0;
        __syncthreads();
        part[t] += v;
        __syncthreads();
    }
    int run = part[t] - s;   // exclusive
    for (int i = 0; i < 20; ++i){
        int idx = base+i;
        if (idx < NN){ rows[idx] = run; run += cnt[idx]; }
    }
    if (t == 0) rows[NN] = EE;
}

__global__ __launch_bounds__(256) void k_fill(const int* src, const int* dst, const int* rows,
                                              int* cursor, int* col){
    int i = blockIdx.x*256 + threadIdx.x;
    if (i < EE){
        int d = dst[i];
        int pos = rows[d] + atomicAdd(&cursor[d], 1);
        col[pos] = src[i];
    }
}

// ---------------- fp32 GEMM  C[M x 128] = A[M x 128] @ W[128 x 128]  + epilogue ----------------
__global__ __launch_bounds__(512) void gemm128(const float* __restrict__ A, const float* __restrict__ Wm,
                                               float* __restrict__ C, int M,
                                               const float* srow, const float* bias,
                                               const float* resid, int relu){
    __shared__ __align__(16) float Ws[128*132];
    __shared__ float As[64*129];
    int tid = threadIdx.x;
    int r0 = blockIdx.x*64;
    for (int i = tid; i < 128*32; i += 512){
        int r = i >> 5, c4 = (i & 31) * 4;
        float4 v = ld4(Wm + r*128 + c4);
        st4(&Ws[r*132 + c4], v);
    }
    for (int i = tid; i < 64*32; i += 512){
        int r = i >> 5, c4 = (i & 31) * 4;
        float4 v = (r0 + r < M) ? ld4(A + (r0+r)*128 + c4) : make_float4(0,0,0,0);
        As[r*129 + c4+0] = v.x; As[r*129 + c4+1] = v.y;
        As[r*129 + c4+2] = v.z; As[r*129 + c4+3] = v.w;
    }
    __syncthreads();
    int a = tid >> 5;
    int b = tid & 31;
    float acc[4][4] = {};
    #pragma unroll 4
    for (int d = 0; d < 128; ++d){
        float4 w = ld4(&Ws[d*132 + 4*b]);
        float wv[4] = {w.x, w.y, w.z, w.w};
        float av[4];
        #pragma unroll
        for (int i = 0; i < 4; ++i) av[i] = As[(4*a+i)*129 + d];
        #pragma unroll
        for (int i = 0; i < 4; ++i)
            #pragma unroll
            for (int j = 0; j < 4; ++j)
                acc[i][j] += av[i]*wv[j];
    }
    int cc = 4*b;
    #pragma unroll
    for (int i = 0; i < 4; ++i){
        int r = r0 + 4*a + i;
        if (r < M){
            float v[4];
            #pragma unroll
            for (int j = 0; j < 4; ++j) v[j] = acc[i][j];
            if (bias){
                #pragma unroll
                for (int j = 0; j < 4; ++j) v[j] += bias[cc+j];
            }
            if (relu){
                #pragma unroll
                for (int j = 0; j < 4; ++j) v[j] = fmaxf(v[j], 0.f);
            }
            if (resid){
                float4 rv = ld4(resid + r*128 + cc);
                v[0]+=rv.x; v[1]+=rv.y; v[2]+=rv.z; v[3]+=rv.w;
            }
            if (srow){
                float sc = srow[r];
                #pragma unroll
                for (int j = 0; j < 4; ++j) v[j] *= sc;
            }
            st4(C + r*128 + cc, make_float4(v[0],v[1],v[2],v[3]));
        }
    }
}

// ---------------- GCN aggregation ----------------
__global__ __launch_bounds__(256) void gcn_agg(const float* __restrict__ hp, const float* __restrict__ dinv,
                                               const int* __restrict__ rows, const int* __restrict__ col,
                                               const float* __restrict__ bias, float* __restrict__ out, int relu){
    int wid = (int)((blockIdx.x*256 + threadIdx.x) >> 6);
    int lane = threadIdx.x & 63;
    if (wid >= NN) return;
    int f = lane*2;
    float2 acc = ld2(hp + wid*128 + f);
    int s = rows[wid], e = rows[wid+1];
    for (int j = s; j < e; ++j){
        int c = col[j];
        float2 v = ld2(hp + c*128 + f);
        acc.x += v.x; acc.y += v.y;
    }
    float dn = dinv[wid];
    float ox = acc.x*dn + bias[f];
    float oy = acc.y*dn + bias[f+1];
    if (relu){ ox = fmaxf(ox, 0.f); oy = fmaxf(oy, 0.f); }
    *reinterpret_cast<float2*>(out + wid*128 + f) = make_float2(ox, oy);
}

// ---------------- convert fp32 -> bf16 (same layout) ----------------
__global__ __launch_bounds__(256) void conv_bf16(const float* __restrict__ in, unsigned short* __restrict__ out, int n4){
    int i = blockIdx.x*256 + threadIdx.x;
    if (i < n4){
        float4 v = ld4(in + i*4);
        ushort4 o;
        o.x = f2bf(v.x); o.y = f2bf(v.y); o.z = f2bf(v.z); o.w = f2bf(v.w);
        *reinterpret_cast<ushort4*>(out + i*4) = o;
    }
}

// ---------------- convert + transpose: fp32 [M x 128] -> bf16 [128 x M] ----------------
__global__ __launch_bounds__(256) void conv_bf16_T(const float* __restrict__ in, unsigned short* __restrict__ out, int M){
    __shared__ float t[64][65];
    int r0 = blockIdx.x*64, c0 = blockIdx.y*64;
    int tid = threadIdx.x;
    for (int i = tid; i < 64*16; i += 256){
        int r = i >> 4, c4 = (i & 15) * 4;
        float4 v = (r0 + r < M) ? ld4(in + (size_t)(r0+r)*128 + c0 + c4) : make_float4(0,0,0,0);
        t[r][c4+0]=v.x; t[r][c4+1]=v.y; t[r][c4+2]=v.z; t[r][c4+3]=v.w;
    }
    __syncthreads();
    for (int i = tid; i < 64*16; i += 256){
        int c = i >> 4, r4 = (i & 15) * 4;
        if (r0 + r4 < M){
            ushort4 o;
            o.x = f2bf(t[r4+0][c]); o.y = f2bf(t[r4+1][c]);
            o.z = f2bf(t[r4+2][c]); o.w = f2bf(t[r4+3][c]);
            *reinterpret_cast<ushort4*>(out + (size_t)(c0+c)*M + r0 + r4) = o;
        }
    }
}

// ---------------- NT MFMA GEMM: C[M x Ncols] = sum_r A[m][r] * B[n][r]  (bf16 in, fp32 acc) ----------------
// register-only: fragments loaded straight from global (contraction dim contiguous in both operands)
// mode 0: store bf16 * scale  (C = ushort*, ldC)
// mode 1: store fp32          (C = float*, ldC)
static __device__ __forceinline__ sh8 ldfrag(const unsigned short* base, int row, int lim, int ld, int off){
    if (row < lim) return *reinterpret_cast<const sh8*>(base + (size_t)row*ld + off);
    sh8 z = (sh8)0;
    return z;
}

__global__ __launch_bounds__(256) void gemm_nt(const unsigned short* __restrict__ A, int ldA, int M,
                                               const unsigned short* __restrict__ B, int ldB, int Ncols,
                                               int R, void* __restrict__ Cv, int ldC, int mode, float scale){
    int tid = threadIdx.x;
    int wave = tid >> 6, lane = tid & 63;
    int wm = wave >> 1, wn = wave & 1;
    int m_base = blockIdx.x*64 + wm*32;
    int n_base = blockIdx.y*64 + wn*32;
    int l15 = lane & 15;
    int roff = (lane >> 4) * 8;
    int rA0 = m_base + l15, rA1 = rA0 + 16;
    int rB0 = n_base + l15, rB1 = rB0 + 16;
    f32x4 acc00 = (f32x4)0.f, acc01 = (f32x4)0.f, acc10 = (f32x4)0.f, acc11 = (f32x4)0.f;
    for (int r = 0; r < R; r += 32){
        sh8 a0 = ldfrag(A, rA0, M, ldA, r + roff);
        sh8 a1 = ldfrag(A, rA1, M, ldA, r + roff);
        sh8 b0 = ldfrag(B, rB0, Ncols, ldB, r + roff);
        sh8 b1 = ldfrag(B, rB1, Ncols, ldB, r + roff);
        acc00 = __builtin_amdgcn_mfma_f32_16x16x32_bf16(a0, b0, acc00, 0, 0, 0);
        acc01 = __builtin_amdgcn_mfma_f32_16x16x32_bf16(a0, b1, acc01, 0, 0, 0);
        acc10 = __builtin_amdgcn_mfma_f32_16x16x32_bf16(a1, b0, acc10, 0, 0, 0);
        acc11 = __builtin_amdgcn_mfma_f32_16x16x32_bf16(a1, b1, acc11, 0, 0, 0);
    }
    int rq = (lane >> 4) * 4;
    f32x4 accs[2][2] = {{acc00, acc01},{acc10, acc11}};
    #pragma unroll
    for (int mi = 0; mi < 2; ++mi){
        #pragma unroll
        for (int ni = 0; ni < 2; ++ni){
            f32x4 a = accs[mi][ni];
            int gn = n_base + ni*16 + l15;
            if (gn >= Ncols) continue;
            #pragma unroll
            for (int reg = 0; reg < 4; ++reg){
                int gm = m_base + mi*16 + rq + reg;
                if (gm < M){
                    if (mode == 0)
                        ((unsigned short*)Cv)[(size_t)gm*ldC + gn] = f2bf(a[reg]*scale);
                    else
                        ((float*)Cv)[(size_t)gm*ldC + gn] = a[reg];
                }
            }
        }
    }
}

// ---------------- row softmax in place on bf16 S [NN x KK] ----------------
__global__ __launch_bounds__(256) void row_softmax(unsigned short* __restrict__ S){
    int row = blockIdx.x*4 + (threadIdx.x >> 6);
    int lane = threadIdx.x & 63;
    if (row >= NN) return;
    unsigned short* p = S + (size_t)row*KK;
    float vals[32];
    int cnt = 0;
    float mx = -1e30f;
    for (int j = lane, i = 0; j < KK; j += 64, ++i){
        float v = bf2f(p[j]);
        vals[i] = v;
        mx = fmaxf(mx, v);
        cnt = i + 1;
    }
    #pragma unroll
    for (int off = 32; off; off >>= 1) mx = fmaxf(mx, __shfl_xor(mx, off));
    float s = 0.f;
    for (int i = 0; i < cnt; ++i){ float e = __expf(vals[i] - mx); vals[i] = e; s += e; }
    #pragma unroll
    for (int off = 32; off; off >>= 1) s += __shfl_xor(s, off);
    float zi = 1.f / s;
    for (int j = lane, i = 0; j < KK; j += 64, ++i) p[j] = f2bf(vals[i]*zi);
}

// ---------------- attn GEMM: attn[kk][d] += sum_n P[n][kk] * Vt[d][n]  (TN, LDS-staged A) ----------------
#define ACHUNKS 625          // 20000 / 32
#define ZSPLIT 32
__global__ __launch_bounds__(256) void attn_gemm(const unsigned short* __restrict__ P,
                                                 const unsigned short* __restrict__ Vt,
                                                 float* __restrict__ attn){
    __shared__ unsigned short As[64*36];
    int tid = threadIdx.x;
    int wave = tid >> 6, lane = tid & 63;
    int kk0 = blockIdx.x*64;
    int per = (ACHUNKS + ZSPLIT - 1) / ZSPLIT;      // 20
    int c0 = blockIdx.y*per;
    int c1 = min(ACHUNKS, c0 + per);
    int l15 = lane & 15;
    int q8 = (lane >> 4) * 8;
    int d0 = wave*32;
    int n_l = tid & 31;
    int k8 = (tid >> 5) * 8;
    f32x4 acc[4][2];
    #pragma unroll
    for (int g = 0; g < 4; ++g){ acc[g][0] = (f32x4)0.f; acc[g][1] = (f32x4)0.f; }
    bool kfull = (kk0 + 63) < KK;
    for (int ch = c0; ch < c1; ++ch){
        int r0 = ch*32;
        // stage P[r0..r0+31][kk0..kk0+63] transposed into As[k][n] (ld 36)
        {
            const unsigned short* prow = P + (size_t)(r0 + n_l)*KK + kk0 + k8;
            unsigned short tmp[8];
            if (kfull){
                *reinterpret_cast<sh8*>(tmp) = *reinterpret_cast<const sh8*>(prow);
            } else {
                #pragma unroll
                for (int j = 0; j < 8; ++j) tmp[j] = (kk0 + k8 + j < KK) ? prow[j] : 0;
            }
            #pragma unroll
            for (int j = 0; j < 8; ++j) As[(k8 + j)*36 + n_l] = tmp[j];
        }
        __syncthreads();
        // B fragments direct from Vt (contiguous in n)
        const unsigned short* vb = Vt + (size_t)(d0 + l15)*NN + r0 + q8;
        sh8 b0 = *reinterpret_cast<const sh8*>(vb);
        sh8 b1 = *reinterpret_cast<const sh8*>(vb + (size_t)16*NN);
        #pragma unroll
        for (int g = 0; g < 4; ++g){
            const unsigned short* ap = &As[(g*16 + l15)*36 + q8];
            union { struct { ushort4 lo, hi; } u; sh8 v; } af;
            af.u.lo = *reinterpret_cast<const ushort4*>(ap);
            af.u.hi = *reinterpret_cast<const ushort4*>(ap + 4);
            acc[g][0] = __builtin_amdgcn_mfma_f32_16x16x32_bf16(af.v, b0, acc[g][0], 0, 0, 0);
            acc[g][1] = __builtin_amdgcn_mfma_f32_16x16x32_bf16(af.v, b1, acc[g][1], 0, 0, 0);
        }
        __syncthreads();
    }
    int rq = (lane >> 4) * 4;
    #pragma unroll
    for (int g = 0; g < 4; ++g){
        #pragma unroll
        for (int ni = 0; ni < 2; ++ni){
            int d = d0 + ni*16 + l15;
            #pragma unroll
            for (int reg = 0; reg < 4; ++reg){
                int kk = kk0 + g*16 + rq + reg;
                if (kk < KK) atomicAdd(&attn[(size_t)kk*128 + d], acc[g][ni][reg]);
            }
        }
    }
}

// ---------------- LayerNorm over D=128 ----------------
__global__ __launch_bounds__(128) void ln_ker(const float* __restrict__ in, const float* __restrict__ resid,
                                              const float* __restrict__ g, const float* __restrict__ be,
                                              float* __restrict__ out){
    __shared__ float rs[128], rq[128];
    int r = blockIdx.x, t = threadIdx.x;
    float v = in[r*128 + t];
    if (resid) v += resid[r*128 + t];
    rs[t] = v; rq[t] = v*v;
    __syncthreads();
    for (int off = 64; off > 0; off >>= 1){
        if (t < off){ rs[t] += rs[t+off]; rq[t] += rq[t+off]; }
        __syncthreads();
    }
    float mean = rs[0]*(1.f/128.f);
    float var = rq[0]*(1.f/128.f) - mean*mean;
    out[r*128 + t] = (v - mean)*rsqrtf(var + 1e-5f)*g[t] + be[t];
}

// ---------------- launcher ----------------
extern "C" void kernel_launch(void* const* d_in, const int* in_sizes, int n_in,
                              void* d_out, int out_size, void* d_ws, size_t ws_size,
                              hipStream_t stream){
    cfp x  = (cfp)d_in[0];
    const int* ei = (const int*)d_in[1];
    const int* esrc = ei;
    const int* edst = ei + EE;
    cfp W1=(cfp)d_in[3], b1=(cfp)d_in[4], W2=(cfp)d_in[5], b2=(cfp)d_in[6];
    cfp S =(cfp)d_in[7];
    cfp Wq=(cfp)d_in[8],  bq=(cfp)d_in[9],  Wk=(cfp)d_in[10], bk=(cfp)d_in[11];
    cfp Wv=(cfp)d_in[12], bv=(cfp)d_in[13], Wo=(cfp)d_in[14], bo=(cfp)d_in[15];
    cfp g0=(cfp)d_in[16], be0=(cfp)d_in[17], g1=(cfp)d_in[18], be1=(cfp)d_in[19];
    cfp Wl=(cfp)d_in[20], bl=(cfp)d_in[21], W3=(cfp)d_in[22], b3=(cfp)d_in[23];
    cfp W4=(cfp)d_in[24], b4=(cfp)d_in[25], W5=(cfp)d_in[26], b5=(cfp)d_in[27];

    char* wsb = (char*)d_ws;
    const size_t MB = 1048576;
    int*   deg    = (int*)  (wsb + 0);
    float* dinv   = (float*)(wsb + 81920);
    int*   rows   = (int*)  (wsb + 163840);
    int*   cursor = (int*)  (wsb + 245760);
    int*   col    = (int*)  (wsb + 327680);
    float* Qb     = (float*)(wsb + 2*MB);
    float* attn   = (float*)(wsb + 4*MB);
    float* o1     = (float*)(wsb + 6*MB);
    float* o2     = (float*)(wsb + 8*MB);
    float* o3     = (float*)(wsb + 10*MB);
    float* xlb    = (float*)(wsb + 12*MB);
    unsigned short* Kbf = (unsigned short*)(wsb + 14*MB);
    unsigned short* Qbf = (unsigned short*)(wsb + 20*MB);
    unsigned short* Vt  = (unsigned short*)(wsb + 21*MB);
    unsigned short* xlt = (unsigned short*)(wsb + 27*MB);
    float* NB0    = (float*)(wsb + 28*MB);
    float* NB1    = (float*)(wsb + 39*MB);
    float* NB2    = (float*)(wsb + 50*MB);
    float* NB3    = (float*)(wsb + 61*MB);
    unsigned short* Sp = (unsigned short*)(wsb + 72*MB);   // S then P, bf16 [NN x KK], 80 MB
    float* outp   = (float*)d_out;

    (void)hipMemsetAsync(deg, 0, NN*sizeof(int), stream);
    (void)hipMemsetAsync(cursor, 0, NN*sizeof(int), stream);
    (void)hipMemsetAsync(attn, 0, KK*128*sizeof(float), stream);

    // CSR build
    k_count<<<1250, 256, 0, stream>>>(edst, deg);
    k_dinv<<<79, 256, 0, stream>>>(deg, dinv);
    k_scan<<<1, 1024, 0, stream>>>(deg, rows);
    k_fill<<<1250, 256, 0, stream>>>(esrc, edst, rows, cursor, col);

    const int GN = 313;   // ceil(NN/64)
    const int GK = 32;    // ceil(KK/64)

    // GCN1: h1 = relu(agg(x@W1 * dinv) * dinv + b1)
    gemm128<<<GN, 512, 0, stream>>>(x, W1, NB0, NN, dinv, nullptr, nullptr, 0);
    gcn_agg<<<5000, 256, 0, stream>>>(NB0, dinv, rows, col, b1, NB1, 1);
    // GCN2 -> h2 in NB2
    gemm128<<<GN, 512, 0, stream>>>(NB1, W2, NB0, NN, dinv, nullptr, nullptr, 0);
    gcn_agg<<<5000, 256, 0, stream>>>(NB0, dinv, rows, col, b2, NB2, 1);
    // Kd = gcn(h2, Wk, bk) -> NB1 -> Kbf
    gemm128<<<GN, 512, 0, stream>>>(NB2, Wk, NB0, NN, dinv, nullptr, nullptr, 0);
    gcn_agg<<<5000, 256, 0, stream>>>(NB0, dinv, rows, col, bk, NB1, 0);
    conv_bf16<<<2500, 256, 0, stream>>>(NB1, Kbf, NN*32);
    // Vd = gcn(h2, Wv, bv) -> NB3 -> Vt (transposed bf16)
    gemm128<<<GN, 512, 0, stream>>>(NB2, Wv, NB0, NN, dinv, nullptr, nullptr, 0);
    gcn_agg<<<5000, 256, 0, stream>>>(NB0, dinv, rows, col, bv, NB3, 0);
    conv_bf16_T<<<dim3(GN, 2), 256, 0, stream>>>(NB3, Vt, NN);
    // Q = S@Wq + bq -> Qb -> Qbf
    gemm128<<<GK, 512, 0, stream>>>(S, Wq, Qb, KK, nullptr, bq, nullptr, 0);
    conv_bf16<<<250, 256, 0, stream>>>(Qb, Qbf, KK*32);
    // S = scale * Kd @ Q^T   (bf16 out, [NN x KK])
    gemm_nt<<<dim3(GN, GK), 256, 0, stream>>>(Kbf, 128, NN, Qbf, 128, KK, 128, Sp, KK, 0, SCALE);
    // softmax over k (rows of Sp), in place -> P
    row_softmax<<<5000, 256, 0, stream>>>(Sp);
    // attn[k][d] = sum_n P[n][k] * V[n][d]
    attn_gemm<<<dim3(GK, ZSPLIT), 256, 0, stream>>>(Sp, Vt, attn);
    // out = LN(Q + attn)
    ln_ker<<<KK, 128, 0, stream>>>(attn, Qb, g0, be0, o1);
    // o2 = o1 + relu(o1@Wo + bo)
    gemm128<<<GK, 512, 0, stream>>>(o1, Wo, o2, KK, nullptr, bo, o1, 1);
    ln_ker<<<KK, 128, 0, stream>>>(o2, nullptr, g1, be1, o3);
    // xl = o3@Wl + bl -> xlb -> xlt (transposed bf16)
    gemm128<<<GK, 512, 0, stream>>>(o3, Wl, xlb, KK, nullptr, bl, nullptr, 0);
    conv_bf16_T<<<dim3(GK, 2), 256, 0, stream>>>(xlb, xlt, KK);
    // x_out[n][d] = sum_k P[n][k] * xl[k][d]   (NT: A=P ld KK, B=xlt ld KK)
    gemm_nt<<<dim3(GN, 2), 256, 0, stream>>>(Sp, KK, NN, xlt, KK, 128, KK, NB0, 128, 1, 1.0f);
    // GCN3
    gemm128<<<GN, 512, 0, stream>>>(NB0, W3, NB1, NN, dinv, nullptr, nullptr, 0);
    gcn_agg<<<5000, 256, 0, stream>>>(NB1, dinv, rows, col, b3, NB2, 1);
    // GCN4
    gemm128<<<GN, 512, 0, stream>>>(NB2, W4, NB0, NN, dinv, nullptr, nullptr, 0);
    gcn_agg<<<5000, 256, 0, stream>>>(NB0, dinv, rows, col, b4, NB1, 1);
    // GCN5 -> d_out
    gemm128<<<GN, 512, 0, stream>>>(NB1, W5, NB0, NN, dinv, nullptr, nullptr, 0);
    gcn_agg<<<5000, 256, 0, stream>>>(NB0, dinv, rows, col, b5, outp, 0);
}